// Round 14
// baseline (58.103 us; speedup 1.0000x reference)
//
#include <hip/hip_runtime.h>
#include <hip/hip_bf16.h>

// Problem constants (Atten_tit): B=16, T=256, K=256, H=512, A=49
#define B_ 16
#define T_ 256
#define K_ 256
#define H_ 512
#define A_ 49
#define APAD 64
#define SC2LOG2E 2.8853900817779268f   // 2*log2(e): pre-scale so sig2 = rcp(exp2(x)+1)

typedef __attribute__((ext_vector_type(8))) short short8;   // bf16x8
typedef __attribute__((ext_vector_type(4))) float f32x4;

__device__ __forceinline__ ushort f2bf(float f) {
    uint u = __builtin_bit_cast(uint, f);
    u += 0x7FFF + ((u >> 16) & 1);   // RNE
    return (ushort)(u >> 16);
}

// 1/(exp2(x)+1) for PRE-SCALED x (x = 2*log2e*arg); tanh(arg) = 1 - 2*sig2s(x).
__device__ __forceinline__ float sig2s(float x) {
    float e = __builtin_amdgcn_exp2f(x);
    return __builtin_amdgcn_rcpf(e + 1.f);
}

// ---------------------------------------------------------------------------
// kW: Wv,Wg (49x512 f32) -> Whl[m][hl][64][512] bf16 (hi + lo residual),
// rows >=49 zeroed. (W keeps full split precision; X side is hi-only.)
__global__ __launch_bounds__(256) void kW(const float* __restrict__ Wv,
                                          const float* __restrict__ Wg,
                                          ushort* __restrict__ Whl)
{
    int blk = blockIdx.x;              // 0..127: m = blk>>6, row = blk&63
    int m = blk >> 6, row = blk & 63;
    const float* W = m ? Wg : Wv;
    int tid = threadIdx.x;
    ushort* hi = Whl + ((size_t)(m * 2 + 0) * 64 + row) * H_;
    ushort* lo = Whl + ((size_t)(m * 2 + 1) * 64 + row) * H_;
    #pragma unroll
    for (int c = tid; c < H_; c += 256) {
        float v = (row < A_) ? W[(size_t)row * H_ + c] : 0.f;
        ushort h = f2bf(v);
        float hf = __builtin_bit_cast(float, (uint)h << 16);
        hi[c] = h;
        lo[c] = f2bf(v - hf);
    }
}

// ---------------------------------------------------------------------------
// kAP: blocks [0,512): projection. X tile (16x512) converted to bf16 (hi only)
//   in LDS once per block; k-loop = {2 W loads (L2), 1 LDS b128, 2 MFMA}.
//   Epilogue scales by 2*log2(e) (consumed only by kZ's sig2s).
//     tiles 0..255   (des):   C = W x des-rows -> cvT (B,64,K)
//     tiles 256..511 (title): C = title-rows x W -> cg (B*T,64)
//   blocks [512,2560): transpose des (B,K,H) f32 -> desT (B,H,K) bf16.
#define XPAD 520   // ushort stride (+8): rows 4 banks apart -> 2-way, free
union UAP {
    ushort xhi[16][XPAD];            // 16640 B
    float  tls[32][33];              // 4224 B
};

__global__ __launch_bounds__(256) void kAP(const float* __restrict__ des,
                                           const float* __restrict__ title,
                                           const ushort* __restrict__ Whl,
                                           float* __restrict__ cvT,
                                           float* __restrict__ cg,
                                           ushort* __restrict__ desT)
{
    __shared__ UAP u;
    int tid = threadIdx.x;

    if (blockIdx.x >= 512) {
        // ---- transpose branch (round-7 proven) ----
        int tb = blockIdx.x - 512;            // b(16) x kt(8) x ht(16)
        int b = tb >> 7, rem = tb & 127;
        int k0 = (rem >> 4) * 32, h0 = (rem & 15) * 32;
        int kk = tid >> 3, c4 = (tid & 7) * 4;
        float4 v = *(const float4*)(des + ((size_t)(b * K_ + k0 + kk) * H_) + h0 + c4);
        u.tls[kk][c4 + 0] = v.x;
        u.tls[kk][c4 + 1] = v.y;
        u.tls[kk][c4 + 2] = v.z;
        u.tls[kk][c4 + 3] = v.w;
        __syncthreads();
        int hh = tid >> 3;
        ushort4 o;
        o.x = f2bf(u.tls[c4 + 0][hh]);
        o.y = f2bf(u.tls[c4 + 1][hh]);
        o.z = f2bf(u.tls[c4 + 2][hh]);
        o.w = f2bf(u.tls[c4 + 3][hh]);
        *(ushort4*)(desT + ((size_t)(b * H_ + h0 + hh) * K_) + k0 + c4) = o;
        return;
    }

    // ---- projection branch ----
    int tile = blockIdx.x;                    // 0..511
    bool isDes = tile < 256;
    const float* Xbase = isDes ? (des + (size_t)tile * 16 * H_)
                               : (title + (size_t)(tile - 256) * 16 * H_);

    {   // stage X tile bf16-hi: 8192 els, 32/thread, coalesced
        #pragma unroll
        for (int it = 0; it < 4; ++it) {
            int eidx = it * 2048 + tid * 8;
            int r = eidx >> 9, c = eidx & 511;
            const float* p = Xbase + (size_t)r * H_ + c;
            float4 v0 = *(const float4*)(p);
            float4 v1 = *(const float4*)(p + 4);
            float vv[8] = {v0.x, v0.y, v0.z, v0.w, v1.x, v1.y, v1.z, v1.w};
            short8 hi;
            #pragma unroll
            for (int i = 0; i < 8; ++i) hi[i] = (short)f2bf(vv[i]);
            *(short8*)&u.xhi[r][c] = hi;
        }
    }
    __syncthreads();

    int wv = tid >> 6, lane = tid & 63;
    int lr = lane & 15, lc = lane >> 4;
    int g = wv;                               // a-group 0..3
    int m = isDes ? 0 : 1;
    const ushort* whiP = Whl + ((size_t)(m * 2 + 0) * 64 + g * 16 + lr) * H_ + lc * 8;
    const ushort* wloP = Whl + ((size_t)(m * 2 + 1) * 64 + g * 16 + lr) * H_ + lc * 8;

    f32x4 acc = {};
    #pragma unroll 4
    for (int k0 = 0; k0 < H_; k0 += 32) {
        short8 whi = *(const short8*)(whiP + k0);
        short8 wlo = *(const short8*)(wloP + k0);
        short8 xhi = *(const short8*)&u.xhi[lr][k0 + lc * 8];
        if (isDes) {     // A = W (rows=a), B = X (cols = k-row of des)
            acc = __builtin_amdgcn_mfma_f32_16x16x32_bf16(whi, xhi, acc, 0, 0, 0);
            acc = __builtin_amdgcn_mfma_f32_16x16x32_bf16(wlo, xhi, acc, 0, 0, 0);
        } else {         // A = X (rows=t), B = W (cols=a)
            acc = __builtin_amdgcn_mfma_f32_16x16x32_bf16(xhi, whi, acc, 0, 0, 0);
            acc = __builtin_amdgcn_mfma_f32_16x16x32_bf16(xhi, wlo, acc, 0, 0, 0);
        }
    }

    if (isDes) {
        int krows = tile * 16;
        int b = krows >> 8, kb = krows & 255;
        #pragma unroll
        for (int r = 0; r < 4; ++r) {
            int a = g * 16 + lc * 4 + r;           // C row = a
            cvT[((size_t)b * APAD + a) * K_ + kb + lr] = acc[r] * SC2LOG2E;
        }
    } else {
        int trows = (tile - 256) * 16;             // global title row (b*T+t)
        #pragma unroll
        for (int r = 0; r < 4; ++r) {
            int row = trows + lc * 4 + r;          // C row = t
            cg[(size_t)row * APAD + g * 16 + lr] = acc[r] * SC2LOG2E;
        }
    }
}

// ---------------------------------------------------------------------------
// kZ: fused z + softmax + PV. 512 blocks x 512 threads (TT=8). b = bid&15
// (XCD-homed; FETCH 3 MB verified R11). Thread (k=tid&255, tg=tid>>8) owns
// t = tg*4 + {0..3}. Ping-pong prefetch of the 8 xa loads hides L2 latency;
// sig2s consumes pre-scaled cvT/cg (no per-eval scale mul).
// PV: 8 waves x 64-h panels, per-j 4-deep B loads.
__global__ __launch_bounds__(512) void kZ(const float* __restrict__ cvT,
                                          const float* __restrict__ cg,
                                          const float* __restrict__ Wh,
                                          const ushort* __restrict__ desT,
                                          float* __restrict__ alpha,
                                          float* __restrict__ chat)
{
    __shared__ float  sCg[8][APAD];        // 2 KB
    __shared__ float  sWh[APAD];
    __shared__ float  sRedM[8][4];
    __shared__ float  sRedS[8][4];
    __shared__ ushort sA[16][K_ + 8];      // 8.4 KB

    int bid = blockIdx.x;                 // 512 blocks
    int b  = bid & 15;
    int t0 = (bid >> 4) * 8;
    int tid = threadIdx.x;
    int k  = tid & 255;
    int tg = tid >> 8;                    // 0..1
    int tb = tg * 4;

    if (tid < 128) {
        int row = tid >> 4, c = (tid & 15) * 4;
        *(float4*)(&sCg[row][c]) =
            *(const float4*)(cg + (size_t)(b * T_ + t0 + row) * APAD + c);
    } else if (tid < 128 + APAD) {
        int a = tid - 128;
        sWh[a] = (a < A_) ? Wh[a] : 0.f;
    }
    {   // zero sA rows 8..15 (PV A-operand has 16 rows; 8 real)
        uint* zp = (uint*)&sA[8][0];      // 8 x 264 ushort = 1056 uint
        #pragma unroll
        for (int i = tid; i < 1056; i += 512) zp[i] = 0;
    }
    __syncthreads();

    // ---- z phase: ping-pong prefetched xa, 4 t's per thread ----
    const float* cvp = cvT + (size_t)b * APAD * K_ + k;
    float zacc[4] = {0.f, 0.f, 0.f, 0.f};
    float xaA[8], xaB[8];
    #pragma unroll
    for (int i = 0; i < 8; ++i) xaA[i] = cvp[(size_t)i * K_];

#define CONSUME(xa, a0) { \
    float4 w0 = *(const float4*)&sWh[(a0)]; \
    float4 w1 = *(const float4*)&sWh[(a0) + 4]; \
    _Pragma("unroll") \
    for (int j = 0; j < 4; ++j) { \
        float4 c0 = *(const float4*)&sCg[tb + j][(a0)]; \
        float4 c1 = *(const float4*)&sCg[tb + j][(a0) + 4]; \
        zacc[j] += w0.x * sig2s(xa[0] + c0.x) + w0.y * sig2s(xa[1] + c0.y) \
                 + w0.z * sig2s(xa[2] + c0.z) + w0.w * sig2s(xa[3] + c0.w) \
                 + w1.x * sig2s(xa[4] + c1.x) + w1.y * sig2s(xa[5] + c1.y) \
                 + w1.z * sig2s(xa[6] + c1.z) + w1.w * sig2s(xa[7] + c1.w); \
    } }

    #pragma unroll
    for (int i = 0; i < 8; ++i) xaB[i] = cvp[(size_t)(8 + i) * K_];
    CONSUME(xaA, 0)
    #pragma unroll
    for (int i = 0; i < 8; ++i) xaA[i] = cvp[(size_t)(16 + i) * K_];
    CONSUME(xaB, 8)
    #pragma unroll
    for (int i = 0; i < 8; ++i) xaB[i] = cvp[(size_t)(24 + i) * K_];
    CONSUME(xaA, 16)
    #pragma unroll
    for (int i = 0; i < 8; ++i) xaA[i] = cvp[(size_t)(32 + i) * K_];
    CONSUME(xaB, 24)
    #pragma unroll
    for (int i = 0; i < 8; ++i) xaB[i] = cvp[(size_t)(40 + i) * K_];
    CONSUME(xaA, 32)
    float xa48 = cvp[(size_t)48 * K_];
    CONSUME(xaB, 40)
#undef CONSUME
    {   // tail a = 48
        float wh = sWh[48];
        #pragma unroll
        for (int j = 0; j < 4; ++j)
            zacc[j] += wh * sig2s(xa48 + sCg[tb + j][48]);
    }
    float sw = 0.f;
    #pragma unroll
    for (int q = 0; q < 16; ++q) {
        float4 w4 = *(const float4*)&sWh[q * 4];
        sw += w4.x + w4.y + w4.z + w4.w;
    }
    float z[4];
    #pragma unroll
    for (int j = 0; j < 4; ++j) z[j] = sw - 2.f * zacc[j];

    // ---- softmax over k (4 waves per tg group) ----
    int wv = tid >> 6, lane = tid & 63, w3 = wv & 3;
    #pragma unroll
    for (int j = 0; j < 4; ++j) {
        float m = z[j];
        #pragma unroll
        for (int off = 32; off > 0; off >>= 1) m = fmaxf(m, __shfl_xor(m, off));
        if (lane == 0) sRedM[tb + j][w3] = m;
    }
    __syncthreads();
    #pragma unroll
    for (int j = 0; j < 4; ++j) {
        int t = tb + j;
        float m = fmaxf(fmaxf(sRedM[t][0], sRedM[t][1]),
                        fmaxf(sRedM[t][2], sRedM[t][3]));
        z[j] = __expf(z[j] - m);
    }
    #pragma unroll
    for (int j = 0; j < 4; ++j) {
        float s = z[j];
        #pragma unroll
        for (int off = 32; off > 0; off >>= 1) s += __shfl_xor(s, off);
        if (lane == 0) sRedS[tb + j][w3] = s;
    }
    __syncthreads();
    #pragma unroll
    for (int j = 0; j < 4; ++j) {
        int t = tb + j;
        float s = sRedS[t][0] + sRedS[t][1] + sRedS[t][2] + sRedS[t][3];
        float rs = __builtin_amdgcn_rcpf(s);
        rs = rs * (2.f - s * rs);              // Newton step
        float al = z[j] * rs;
        alpha[(size_t)(b * T_ + t0 + t) * K_ + k] = al;
        sA[t][k] = f2bf(al);
    }
    __syncthreads();

    // ---- PV: wave wv -> h-panel [wv*64, +64), per-j 4-deep B loads ----
    int lr = lane & 15, lc = lane >> 4;
    int h0 = wv * 64;
    const ushort* Bp = desT + ((size_t)(b * H_ + h0 + lr)) * K_ + lc * 8;

    short8 af[8];
    #pragma unroll
    for (int s = 0; s < 8; ++s)
        af[s] = *(const short8*)(&sA[lr][s * 32 + lc * 8]);

    f32x4 acc[4] = {};
    #pragma unroll
    for (int j = 0; j < 4; ++j) {
        const ushort* Bj = Bp + (size_t)(j * 16) * K_;
        short8 bf[8];
        #pragma unroll
        for (int s = 0; s < 8; ++s)
            bf[s] = *(const short8*)(Bj + s * 32);
        #pragma unroll
        for (int s = 0; s < 8; ++s)
            acc[j] = __builtin_amdgcn_mfma_f32_16x16x32_bf16(af[s], bf[s], acc[j], 0, 0, 0);
    }

    #pragma unroll
    for (int j = 0; j < 4; ++j) {
        #pragma unroll
        for (int r = 0; r < 4; ++r) {
            int row = lc * 4 + r;
            if (row < 8)
                chat[((size_t)(b * T_ + t0 + row)) * H_ + h0 + j * 16 + lr] = acc[j][r];
        }
    }
}

// ---------------------------------------------------------------------------
extern "C" void kernel_launch(void* const* d_in, const int* in_sizes, int n_in,
                              void* d_out, int out_size, void* d_ws, size_t ws_size,
                              hipStream_t stream) {
    const float* des   = (const float*)d_in[0];
    const float* title = (const float*)d_in[1];
    const float* Wv    = (const float*)d_in[2];
    const float* Wg    = (const float*)d_in[3];
    const float* Wh    = (const float*)d_in[4];

    float* chat  = (float*)d_out;                            // (B,T,H)
    float* alpha = (float*)d_out + (size_t)B_ * T_ * H_;     // (B,T,K)

    char* ws = (char*)d_ws;
    float*  cvT  = (float*)ws;                               // (B,64,K) f32: 1 MB
    float*  cg   = cvT + (size_t)B_ * APAD * K_;             // (B*T,64) f32: 1 MB
    ushort* desT = (ushort*)(cg + (size_t)B_ * T_ * APAD);   // (B,H,K) bf16: 4 MB
    ushort* Whl  = desT + (size_t)B_ * H_ * K_;              // [2][2][64][512]: 256 KB

    hipLaunchKernelGGL(kW, dim3(128), dim3(256), 0, stream, Wv, Wg, Whl);
    hipLaunchKernelGGL(kAP, dim3(2560), dim3(256), 0, stream,
                       des, title, Whl, cvT, cg, desT);
    hipLaunchKernelGGL(kZ, dim3(2 * B_ * (T_ / 16)), dim3(512), 0, stream,
                       cvT, cg, Wh, desT, alpha, chat);
}